// Round 4
// baseline (1759.226 us; speedup 1.0000x reference)
//
#include <hip/hip_runtime.h>
#include <cstdint>

// Problem constants (from reference)
#define Bsz       4096
#define Nn        4
#define EMBED     2048
#define DFF       8192
#define INPUT_DIM 8192
#define BLOCKD    2048
#define EPSf      1.1920929e-7f

typedef short bf16x8 __attribute__((ext_vector_type(8)));
typedef float f32x4  __attribute__((ext_vector_type(4)));

typedef __attribute__((address_space(3))) void* lds_vp;
typedef __attribute__((address_space(1))) void* gbl_vp;

__device__ __forceinline__ float sigmoidf_(float v) { return 1.0f / (1.0f + expf(-v)); }
__device__ __forceinline__ float gelu_tanh(float v) {
    const float c = 0.7978845608028654f;  // sqrt(2/pi)
    float t = tanhf(c * (v + 0.044715f * v * v * v));
    return 0.5f * v * (1.0f + t);
}
__device__ __forceinline__ float dot4(float4 a, float4 b) {
    return a.x * b.x + a.y * b.y + a.z * b.z + a.w * b.w;
}
// bf16 split helpers (truncation split: v ~= hi + lo, |resid| <= 2^-16 |v|)
__device__ __forceinline__ unsigned short f2bf(float f) {
    union { float f; unsigned u; } c; c.f = f; return (unsigned short)(c.u >> 16);
}
__device__ __forceinline__ float bf2f(unsigned short h) {
    union { float f; unsigned u; } c; c.u = ((unsigned)h) << 16; return c.f;
}

// global->LDS direct copy, 16B/lane. HW writes lane i to ldsbase + i*16
// [m97/m104]. LDS ptr must be wave-uniform; global src is per-lane.
// Cast chain: strip const via (void*), then addrspace-cast; LDS side is a
// true generic->AS3 addrspacecast (numeric cast would keep the aperture).
__device__ __forceinline__ void gload16(const void* g, void* l) {
    __builtin_amdgcn_global_load_lds((gbl_vp)(void*)g, (lds_vp)l, 16, 0, 0);
}

// ---------------------------------------------------------------------------
// Kernel 1: per-row stats + scalar chain -> phi[B,16], ri[B,4], wo[B,4].
// 4 batch rows per block: each weight float4 is loaded once and reused for
// 4 in-register x-vectors (L2 weight traffic 4 GB -> 1 GB).
// acc[r][0]=sum(x^2); [r][1..4]=W_ri; [5..8]=W_wo; [9..24]=W_conv;
// [25]=W_dtc; [26]=W_dtd; [27..30]=W_diss
// ---------------------------------------------------------------------------
__global__ __launch_bounds__(256) void rowstats_kernel(
    const float* __restrict__ x,
    const float* __restrict__ read_in_p, const float* __restrict__ write_out_p,
    const float* __restrict__ alpha_ri, const float* __restrict__ alpha_wo,
    const float* __restrict__ W_ri, const float* __restrict__ W_wo,
    const float* __restrict__ log_dt_c, const float* __restrict__ log_dt_d,
    const float* __restrict__ W_dtc, const float* __restrict__ b_dtc,
    const float* __restrict__ W_dtd, const float* __restrict__ b_dtd,
    const float* __restrict__ conserv_A, const float* __restrict__ W_conv,
    const float* __restrict__ diss_diag, const float* __restrict__ W_diss,
    float* __restrict__ phi_out, float* __restrict__ ri_out, float* __restrict__ wo_out)
{
    const int b0  = blockIdx.x * 4;
    const int tid = threadIdx.x;

    float acc[4][31];
#pragma unroll
    for (int r = 0; r < 4; ++r)
#pragma unroll
        for (int j = 0; j < 31; ++j) acc[r][j] = 0.0f;

#pragma unroll 1
    for (int i = 0; i < 8; ++i) {
        const int e = i * 1024 + tid * 4;
        float4 xv[4];
#pragma unroll
        for (int r = 0; r < 4; ++r) {
            xv[r] = *(const float4*)(x + (size_t)(b0 + r) * INPUT_DIM + e);
            acc[r][0] += dot4(xv[r], xv[r]);
        }
#pragma unroll
        for (int w = 0; w < 4; ++w) {
            const float4 wv = *(const float4*)(W_ri + (size_t)w * INPUT_DIM + e);
#pragma unroll
            for (int r = 0; r < 4; ++r) acc[r][1 + w] += dot4(xv[r], wv);
        }
#pragma unroll
        for (int w = 0; w < 4; ++w) {
            const float4 wv = *(const float4*)(W_wo + (size_t)w * INPUT_DIM + e);
#pragma unroll
            for (int r = 0; r < 4; ++r) acc[r][5 + w] += dot4(xv[r], wv);
        }
#pragma unroll
        for (int w = 0; w < 16; ++w) {
            const float4 wv = *(const float4*)(W_conv + (size_t)w * INPUT_DIM + e);
#pragma unroll
            for (int r = 0; r < 4; ++r) acc[r][9 + w] += dot4(xv[r], wv);
        }
        {
            const float4 wv = *(const float4*)(W_dtc + e);
#pragma unroll
            for (int r = 0; r < 4; ++r) acc[r][25] += dot4(xv[r], wv);
        }
        {
            const float4 wv = *(const float4*)(W_dtd + e);
#pragma unroll
            for (int r = 0; r < 4; ++r) acc[r][26] += dot4(xv[r], wv);
        }
#pragma unroll
        for (int w = 0; w < 4; ++w) {
            const float4 wv = *(const float4*)(W_diss + (size_t)w * INPUT_DIM + e);
#pragma unroll
            for (int r = 0; r < 4; ++r) acc[r][27 + w] += dot4(xv[r], wv);
        }
    }

    // wave butterfly (result in lane 0), then cross-wave via LDS
#pragma unroll
    for (int r = 0; r < 4; ++r)
#pragma unroll
        for (int j = 0; j < 31; ++j) {
            float v = acc[r][j];
#pragma unroll
            for (int o = 32; o > 0; o >>= 1) v += __shfl_down(v, o, 64);
            acc[r][j] = v;
        }
    __shared__ float red[4][4][31];   // [wave][row][j]
    const int wave = tid >> 6, lane = tid & 63;
    if (lane == 0) {
#pragma unroll
        for (int r = 0; r < 4; ++r)
#pragma unroll
            for (int j = 0; j < 31; ++j) red[wave][r][j] = acc[r][j];
    }
    __syncthreads();

    if (tid < 4) {
        const int r = tid;
        const int b = b0 + r;
        float s31[31];
#pragma unroll
        for (int j = 0; j < 31; ++j)
            s31[j] = red[0][r][j] + red[1][r][j] + red[2][r][j] + red[3][r][j];

        const float s = 1.0f / sqrtf(s31[0] * (1.0f / (float)INPUT_DIM) + EPSf);

        const float a_ri = alpha_ri[0], a_wo = alpha_wo[0];
        float ri[Nn], wo[Nn];
#pragma unroll
        for (int n = 0; n < Nn; ++n) {
            ri[n] = sigmoidf_(a_ri * (s * s31[1 + n]) + read_in_p[n]);
            wo[n] = 2.0f * sigmoidf_(a_wo * (s * s31[5 + n]) + write_out_p[n]);
        }

        const float dt_c = 1e-3f + (1.0f - 1e-3f) * sigmoidf_(log_dt_c[0] + s * s31[25] + b_dtc[0]);
        const float dt_d = 1e-3f + (1.0f - 1e-3f) * sigmoidf_(log_dt_d[0] + s * s31[26] + b_dtd[0]);

        float Mmat[Nn][Nn];
#pragma unroll
        for (int i = 0; i < Nn; ++i)
#pragma unroll
            for (int j = 0; j < Nn; ++j)
                Mmat[i][j] = conserv_A[i * Nn + j] + s * s31[9 + i * Nn + j];

        float S[Nn][Nn];
#pragma unroll
        for (int i = 0; i < Nn; ++i)
#pragma unroll
            for (int j = 0; j < Nn; ++j)
                S[i][j] = dt_c * 0.5f * (Mmat[i][j] - Mmat[j][i]);

        float ehD[Nn];
#pragma unroll
        for (int n = 0; n < Nn; ++n) {
            const float v = diss_diag[n] + s * s31[27 + n];
            const float sp = (v > 20.0f) ? v : log1pf(expf(v));  // softplus
            ehD[n] = expf(-0.5f * dt_d * sp);
        }

        // Solve (I-S)X = (I+S), Gauss-Jordan. I-S has unit diagonal (S skew),
        // |S_ij| ~ 0.03 -> diagonally dominant, no pivoting needed.
        float Am[Nn][Nn], X[Nn][Nn];
#pragma unroll
        for (int i = 0; i < Nn; ++i)
#pragma unroll
            for (int j = 0; j < Nn; ++j) {
                const float id = (i == j) ? 1.0f : 0.0f;
                Am[i][j] = id - S[i][j];
                X[i][j]  = id + S[i][j];
            }
#pragma unroll
        for (int c = 0; c < Nn; ++c) {
            const float inv = 1.0f / Am[c][c];
#pragma unroll
            for (int j = 0; j < Nn; ++j) { Am[c][j] *= inv; X[c][j] *= inv; }
#pragma unroll
            for (int rr = 0; rr < Nn; ++rr) {
                if (rr == c) continue;
                const float f = Am[rr][c];
#pragma unroll
                for (int j = 0; j < Nn; ++j) { Am[rr][j] -= f * Am[c][j]; X[rr][j] -= f * X[c][j]; }
            }
        }

        float* __restrict__ P = phi_out + (size_t)b * 16;
#pragma unroll
        for (int i = 0; i < Nn; ++i)
#pragma unroll
            for (int j = 0; j < Nn; ++j)
                P[i * Nn + j] = ehD[i] * X[i][j] * ehD[j];
#pragma unroll
        for (int n = 0; n < Nn; ++n) {
            ri_out[(size_t)b * Nn + n] = ri[n];
            wo_out[(size_t)b * Nn + n] = wo[n];
        }
    }
}

// ---------------------------------------------------------------------------
// Kernel 2: branch[b,d] = sum_n ri[b,n]*x[b,n,d], emitted as bf16 hi/lo
// ---------------------------------------------------------------------------
__global__ __launch_bounds__(256) void branch_kernel(
    const float* __restrict__ x, const float* __restrict__ ri,
    unsigned short* __restrict__ bh, unsigned short* __restrict__ bl)
{
    const int g = blockIdx.x * 256 + threadIdx.x;   // over B * 512
    const int b = g >> 9;
    const int d = (g & 511) << 2;
    const float* __restrict__ xb = x + (size_t)b * INPUT_DIM;
    const float* __restrict__ r  = ri + (size_t)b * Nn;
    float4 o = make_float4(0.f, 0.f, 0.f, 0.f);
#pragma unroll
    for (int n = 0; n < Nn; ++n) {
        const float4 xv = *(const float4*)(xb + n * BLOCKD + d);
        const float rn = r[n];
        o.x = fmaf(rn, xv.x, o.x);
        o.y = fmaf(rn, xv.y, o.y);
        o.z = fmaf(rn, xv.z, o.z);
        o.w = fmaf(rn, xv.w, o.w);
    }
    ushort4 h4, l4;
    h4.x = f2bf(o.x); l4.x = f2bf(o.x - bf2f(h4.x));
    h4.y = f2bf(o.y); l4.y = f2bf(o.y - bf2f(h4.y));
    h4.z = f2bf(o.z); l4.z = f2bf(o.z - bf2f(h4.z));
    h4.w = f2bf(o.w); l4.w = f2bf(o.w - bf2f(h4.w));
    *(ushort4*)(bh + (size_t)b * EMBED + d) = h4;
    *(ushort4*)(bl + (size_t)b * EMBED + d) = l4;
}

// ---------------------------------------------------------------------------
// Kernel 3: weight transpose+split. in fp32 [R][C] -> out bf16 hi/lo [C][R]
// ---------------------------------------------------------------------------
__global__ __launch_bounds__(256) void tconv_kernel(
    const float* __restrict__ in,
    unsigned short* __restrict__ oh, unsigned short* __restrict__ ol,
    int R, int C)
{
    __shared__ float t[32][33];
    const int c0 = blockIdx.x * 32;
    const int r0 = blockIdx.y * 32;
    const int tr  = threadIdx.x >> 3;        // 0..31
    const int tc4 = (threadIdx.x & 7) * 4;   // 0..28
    const float4 v = *(const float4*)(in + (size_t)(r0 + tr) * C + c0 + tc4);
    t[tr][tc4 + 0] = v.x;
    t[tr][tc4 + 1] = v.y;
    t[tr][tc4 + 2] = v.z;
    t[tr][tc4 + 3] = v.w;
    __syncthreads();
    ushort4 h4, l4;
    {
        const float f0 = t[tc4 + 0][tr], f1 = t[tc4 + 1][tr];
        const float f2 = t[tc4 + 2][tr], f3 = t[tc4 + 3][tr];
        h4.x = f2bf(f0); l4.x = f2bf(f0 - bf2f(h4.x));
        h4.y = f2bf(f1); l4.y = f2bf(f1 - bf2f(h4.y));
        h4.z = f2bf(f2); l4.z = f2bf(f2 - bf2f(h4.z));
        h4.w = f2bf(f3); l4.w = f2bf(f3 - bf2f(h4.w));
    }
    const size_t ob = (size_t)(c0 + tr) * R + r0 + tc4;
    *(ushort4*)(oh + ob) = h4;
    *(ushort4*)(ol + ob) = l4;
}

// ---------------------------------------------------------------------------
// Kernel 4/5: bf16x3 MFMA GEMM. C = Ah*Bh + Ah*Bl + Al*Bh (lo*lo dropped,
// ~2^-16 rel). A row-major [M][K] bf16; B stored TRANSPOSED [N][K] bf16.
// 128x128 tile, BK=32, 4 waves 2x2, 4x4 16x16x32 frags/wave.
// Double-buffered LDS via global_load_lds width-16; one barrier per K-step.
// A/B fragment k-permutation cancels (same lane->k map both operands);
// C/D layout col=lane&15, row=(lane>>4)*4+j [m89/m91].
// GELU=true: epilogue applies tanh-gelu, writes bf16 hi/lo (GEMM2's A).
// ---------------------------------------------------------------------------
template <int K, bool GELU>
__global__ __launch_bounds__(256) void gemm_bf16x3_kernel(
    const unsigned short* __restrict__ Ah, const unsigned short* __restrict__ Al,
    const unsigned short* __restrict__ Bh, const unsigned short* __restrict__ Bl,
    float* __restrict__ Cf,
    unsigned short* __restrict__ Ch, unsigned short* __restrict__ Cl,
    int N)
{
    constexpr int KSTEPS = K / 32;
    constexpr int TSTEPS = 3 * KSTEPS;
    // 2 bufs x (A 4096 + B 4096 shorts) = 32 KiB
    __shared__ alignas(16) unsigned short smem[16384];

    const int tid = threadIdx.x;
    const int l   = tid & 63;
    const int w   = tid >> 6;
    const int wr  = w >> 1, wc = w & 1;

    // XCD-aware bijective swizzle (nwg % 8 == 0 for both GEMMs) [T1]
    const int nwg = gridDim.x * gridDim.y;
    int lin = blockIdx.y * gridDim.x + blockIdx.x;
    lin = (lin & 7) * (nwg >> 3) + (lin >> 3);
    const int bx = lin % gridDim.x;
    const int by = lin / gridDim.x;
    const int row0 = by * 128;
    const int col0 = bx * 128;

    const int srow = l >> 2;        // staging: row-in-chunk 0..15
    const int skq  = (l & 3) * 8;   // staging: k offset in shorts

    f32x4 acc[4][4];
    const f32x4 z4 = {0.f, 0.f, 0.f, 0.f};
#pragma unroll
    for (int m = 0; m < 4; ++m)
#pragma unroll
        for (int n = 0; n < 4; ++n) acc[m][n] = z4;

    // stage one 128x32 A-tile + 128x32 B-tile into LDS buffer `buf`.
    // chunk = 16 rows x 32 shorts = 1024 B = one wave-wide gload16.
    auto stage = [&](int t, int buf) {
        const int s  = t / KSTEPS;                 // 0:AhBh 1:AhBl 2:AlBh
        const int kk = (t - s * KSTEPS) * 32;
        const unsigned short* Ap = (s == 2) ? Al : Ah;
        const unsigned short* Bp = (s == 1) ? Bl : Bh;
        unsigned short* base = smem + buf * 8192;
#pragma unroll
        for (int i = 0; i < 2; ++i) {
            const int c = 2 * w + i;  // chunk 0..7 (uniform per wave)
            gload16(Ap + (size_t)(row0 + c * 16 + srow) * K + kk + skq,
                    base + c * 512);
            gload16(Bp + (size_t)(col0 + c * 16 + srow) * K + kk + skq,
                    base + 4096 + c * 512);
        }
    };

    stage(0, 0);
    int cur = 0;
    const int kg8 = (l >> 4) * 8;
    const int fr  = l & 15;
    for (int t = 0; t < TSTEPS; ++t) {
        // __syncthreads emits full vmcnt/lgkmcnt drain before s_barrier:
        // all waves' stage(t) writes are visible after this.
        __syncthreads();
        if (t + 1 < TSTEPS) stage(t + 1, cur ^ 1);

        const unsigned short* As = smem + cur * 8192;
        const unsigned short* Bs = smem + cur * 8192 + 4096;
        bf16x8 a[4], b[4];
#pragma unroll
        for (int m = 0; m < 4; ++m)
            a[m] = *(const bf16x8*)(As + (wr * 64 + m * 16 + fr) * 32 + kg8);
#pragma unroll
        for (int n = 0; n < 4; ++n)
            b[n] = *(const bf16x8*)(Bs + (wc * 64 + n * 16 + fr) * 32 + kg8);
#pragma unroll
        for (int m = 0; m < 4; ++m)
#pragma unroll
            for (int n = 0; n < 4; ++n)
                acc[m][n] = __builtin_amdgcn_mfma_f32_16x16x32_bf16(a[m], b[n], acc[m][n], 0, 0, 0);
        cur ^= 1;
    }

    // Epilogue. D frag layout: col = lane&15, row = (lane>>4)*4 + j [m89/m91]
#pragma unroll
    for (int m = 0; m < 4; ++m) {
        const int gr0 = row0 + wr * 64 + m * 16 + (l >> 4) * 4;
#pragma unroll
        for (int j = 0; j < 4; ++j) {
            const size_t rb = (size_t)(gr0 + j) * N;
#pragma unroll
            for (int n = 0; n < 4; ++n) {
                const int gc = col0 + wc * 64 + n * 16 + fr;
                float v = acc[m][n][j];
                if (GELU) {
                    v = gelu_tanh(v);
                    const unsigned short h = f2bf(v);
                    Ch[rb + gc] = h;
                    Cl[rb + gc] = f2bf(v - bf2f(h));
                } else {
                    Cf[rb + gc] = v;
                }
            }
        }
    }
}

// ---------------------------------------------------------------------------
// Kernel 6: out[b,i,d] = sum_j Phi[b,i,j]*x[b,j,d] + wo[b,i]*y[b,d]
// ---------------------------------------------------------------------------
__global__ __launch_bounds__(256) void output_kernel(
    const float* __restrict__ x, const float* __restrict__ phi,
    const float* __restrict__ wo, const float* __restrict__ y,
    float* __restrict__ out)
{
    const int g = blockIdx.x * 256 + threadIdx.x;  // over B * 512
    const int b = g >> 9;
    const int d = (g & 511) << 2;
    const float* __restrict__ xb = x + (size_t)b * INPUT_DIM;
    float4 xj[Nn];
#pragma unroll
    for (int j = 0; j < Nn; ++j) xj[j] = *(const float4*)(xb + j * BLOCKD + d);
    const float4 yv = *(const float4*)(y + (size_t)b * EMBED + d);
    const float* __restrict__ P = phi + (size_t)b * 16;
    const float* __restrict__ wv = wo + (size_t)b * Nn;
    float* __restrict__ ob = out + (size_t)b * INPUT_DIM;
#pragma unroll
    for (int i = 0; i < Nn; ++i) {
        const float wi = wv[i];
        float4 o;
        o.x = wi * yv.x; o.y = wi * yv.y; o.z = wi * yv.z; o.w = wi * yv.w;
#pragma unroll
        for (int j = 0; j < Nn; ++j) {
            const float p = P[i * Nn + j];
            o.x = fmaf(p, xj[j].x, o.x);
            o.y = fmaf(p, xj[j].y, o.y);
            o.z = fmaf(p, xj[j].z, o.z);
            o.w = fmaf(p, xj[j].w, o.w);
        }
        *(float4*)(ob + i * BLOCKD + d) = o;
    }
}

// ---------------------------------------------------------------------------
extern "C" void kernel_launch(void* const* d_in, const int* in_sizes, int n_in,
                              void* d_out, int out_size, void* d_ws, size_t ws_size,
                              hipStream_t stream)
{
    const float* x          = (const float*)d_in[0];
    const float* read_in_p  = (const float*)d_in[1];
    const float* write_out_p= (const float*)d_in[2];
    const float* alpha_ri   = (const float*)d_in[3];
    const float* alpha_wo   = (const float*)d_in[4];
    const float* W_ri       = (const float*)d_in[5];
    const float* W_wo       = (const float*)d_in[6];
    const float* log_dt_c   = (const float*)d_in[7];
    const float* log_dt_d   = (const float*)d_in[8];
    const float* W_dtc      = (const float*)d_in[9];
    const float* b_dtc      = (const float*)d_in[10];
    const float* W_dtd      = (const float*)d_in[11];
    const float* b_dtd      = (const float*)d_in[12];
    const float* conserv_A  = (const float*)d_in[13];
    const float* W_conv     = (const float*)d_in[14];
    const float* diss_diag  = (const float*)d_in[15];
    const float* W_diss     = (const float*)d_in[16];
    const float* W1         = (const float*)d_in[17];
    const float* W2         = (const float*)d_in[18];

    // workspace layout (bytes, 256-aligned), total ~335 MB
    char* p = (char*)d_ws;
    auto alloc = [&](size_t bytes) { char* r = p; p += (bytes + 255) & ~(size_t)255; return r; };
    float*          phi = (float*)alloc((size_t)Bsz * 16 * 4);
    float*          ri  = (float*)alloc((size_t)Bsz * Nn * 4);
    float*          wo  = (float*)alloc((size_t)Bsz * Nn * 4);
    unsigned short* bh  = (unsigned short*)alloc((size_t)Bsz * EMBED * 2);
    unsigned short* bl  = (unsigned short*)alloc((size_t)Bsz * EMBED * 2);
    unsigned short* W1h = (unsigned short*)alloc((size_t)DFF * EMBED * 2);   // [8192][2048]
    unsigned short* W1l = (unsigned short*)alloc((size_t)DFF * EMBED * 2);
    unsigned short* W2h = (unsigned short*)alloc((size_t)EMBED * DFF * 2);   // [2048][8192]
    unsigned short* W2l = (unsigned short*)alloc((size_t)EMBED * DFF * 2);
    unsigned short* hh  = (unsigned short*)alloc((size_t)Bsz * DFF * 2);     // [4096][8192]
    unsigned short* hl  = (unsigned short*)alloc((size_t)Bsz * DFF * 2);
    float*          y   = (float*)alloc((size_t)Bsz * EMBED * 4);
    float*          outp = (float*)d_out;

    rowstats_kernel<<<Bsz / 4, 256, 0, stream>>>(
        x, read_in_p, write_out_p, alpha_ri, alpha_wo, W_ri, W_wo,
        log_dt_c, log_dt_d, W_dtc, b_dtc, W_dtd, b_dtd,
        conserv_A, W_conv, diss_diag, W_diss, phi, ri, wo);

    // W1 [2048][8192] -> hi/lo [8192][2048]; W2 [8192][2048] -> hi/lo [2048][8192]
    tconv_kernel<<<dim3(DFF / 32, EMBED / 32), 256, 0, stream>>>(W1, W1h, W1l, EMBED, DFF);
    tconv_kernel<<<dim3(EMBED / 32, DFF / 32), 256, 0, stream>>>(W2, W2h, W2l, DFF, EMBED);

    branch_kernel<<<(Bsz * 512) / 256, 256, 0, stream>>>(x, ri, bh, bl);

    // GEMM1: h = gelu(branch @ W1), M=4096 N=8192 K=2048 -> hh/hl bf16
    gemm_bf16x3_kernel<EMBED, true><<<dim3(DFF / 128, Bsz / 128), 256, 0, stream>>>(
        bh, bl, W1h, W1l, nullptr, hh, hl, DFF);

    // GEMM2: y = h @ W2, M=4096 N=2048 K=8192 -> fp32
    gemm_bf16x3_kernel<DFF, false><<<dim3(EMBED / 128, Bsz / 128), 256, 0, stream>>>(
        hh, hl, W2h, W2l, y, nullptr, nullptr, EMBED);

    output_kernel<<<(Bsz * 512) / 256, 256, 0, stream>>>(x, phi, wo, y, outp);
}

// Round 6
// 1437.450 us; speedup vs baseline: 1.2239x; 1.2239x over previous
//
#include <hip/hip_runtime.h>
#include <cstdint>

// Problem constants (from reference)
#define Bsz       4096
#define Nn        4
#define EMBED     2048
#define DFF       8192
#define INPUT_DIM 8192
#define BLOCKD    2048
#define EPSf      1.1920929e-7f

typedef short bf16x8 __attribute__((ext_vector_type(8)));
typedef float f32x4  __attribute__((ext_vector_type(4)));

typedef __attribute__((address_space(3))) void* lds_vp;
typedef __attribute__((address_space(1))) void* gbl_vp;

__device__ __forceinline__ float sigmoidf_(float v) { return 1.0f / (1.0f + expf(-v)); }
__device__ __forceinline__ float gelu_tanh(float v) {
    const float c = 0.7978845608028654f;  // sqrt(2/pi)
    float t = tanhf(c * (v + 0.044715f * v * v * v));
    return 0.5f * v * (1.0f + t);
}
__device__ __forceinline__ float dot4(float4 a, float4 b) {
    return a.x * b.x + a.y * b.y + a.z * b.z + a.w * b.w;
}
// bf16 split helpers (truncation split: v ~= hi + lo, |resid| <= 2^-16 |v|)
__device__ __forceinline__ unsigned short f2bf(float f) {
    union { float f; unsigned u; } c; c.f = f; return (unsigned short)(c.u >> 16);
}
__device__ __forceinline__ float bf2f(unsigned short h) {
    union { float f; unsigned u; } c; c.u = ((unsigned)h) << 16; return c.f;
}

// global->LDS direct copy, 16B/lane. HW writes lane i to ldsbase + i*16
// [m97/m104]. LDS ptr must be wave-uniform; global src is per-lane.
__device__ __forceinline__ void gload16(const void* g, void* l) {
    __builtin_amdgcn_global_load_lds((gbl_vp)(void*)g, (lds_vp)l, 16, 0, 0);
}

// ---------------------------------------------------------------------------
// Kernel 1: per-row stats + scalar chain -> phi[B,16], ri[B,4], wo[B,4].
// 4 batch rows per block; weight float4 loaded once per 4 rows.
// ---------------------------------------------------------------------------
__global__ __launch_bounds__(256) void rowstats_kernel(
    const float* __restrict__ x,
    const float* __restrict__ read_in_p, const float* __restrict__ write_out_p,
    const float* __restrict__ alpha_ri, const float* __restrict__ alpha_wo,
    const float* __restrict__ W_ri, const float* __restrict__ W_wo,
    const float* __restrict__ log_dt_c, const float* __restrict__ log_dt_d,
    const float* __restrict__ W_dtc, const float* __restrict__ b_dtc,
    const float* __restrict__ W_dtd, const float* __restrict__ b_dtd,
    const float* __restrict__ conserv_A, const float* __restrict__ W_conv,
    const float* __restrict__ diss_diag, const float* __restrict__ W_diss,
    float* __restrict__ phi_out, float* __restrict__ ri_out, float* __restrict__ wo_out)
{
    const int b0  = blockIdx.x * 4;
    const int tid = threadIdx.x;

    float acc[4][31];
#pragma unroll
    for (int r = 0; r < 4; ++r)
#pragma unroll
        for (int j = 0; j < 31; ++j) acc[r][j] = 0.0f;

#pragma unroll 1
    for (int i = 0; i < 8; ++i) {
        const int e = i * 1024 + tid * 4;
        float4 xv[4];
#pragma unroll
        for (int r = 0; r < 4; ++r) {
            xv[r] = *(const float4*)(x + (size_t)(b0 + r) * INPUT_DIM + e);
            acc[r][0] += dot4(xv[r], xv[r]);
        }
#pragma unroll
        for (int w = 0; w < 4; ++w) {
            const float4 wv = *(const float4*)(W_ri + (size_t)w * INPUT_DIM + e);
#pragma unroll
            for (int r = 0; r < 4; ++r) acc[r][1 + w] += dot4(xv[r], wv);
        }
#pragma unroll
        for (int w = 0; w < 4; ++w) {
            const float4 wv = *(const float4*)(W_wo + (size_t)w * INPUT_DIM + e);
#pragma unroll
            for (int r = 0; r < 4; ++r) acc[r][5 + w] += dot4(xv[r], wv);
        }
#pragma unroll
        for (int w = 0; w < 16; ++w) {
            const float4 wv = *(const float4*)(W_conv + (size_t)w * INPUT_DIM + e);
#pragma unroll
            for (int r = 0; r < 4; ++r) acc[r][9 + w] += dot4(xv[r], wv);
        }
        {
            const float4 wv = *(const float4*)(W_dtc + e);
#pragma unroll
            for (int r = 0; r < 4; ++r) acc[r][25] += dot4(xv[r], wv);
        }
        {
            const float4 wv = *(const float4*)(W_dtd + e);
#pragma unroll
            for (int r = 0; r < 4; ++r) acc[r][26] += dot4(xv[r], wv);
        }
#pragma unroll
        for (int w = 0; w < 4; ++w) {
            const float4 wv = *(const float4*)(W_diss + (size_t)w * INPUT_DIM + e);
#pragma unroll
            for (int r = 0; r < 4; ++r) acc[r][27 + w] += dot4(xv[r], wv);
        }
    }

#pragma unroll
    for (int r = 0; r < 4; ++r)
#pragma unroll
        for (int j = 0; j < 31; ++j) {
            float v = acc[r][j];
#pragma unroll
            for (int o = 32; o > 0; o >>= 1) v += __shfl_down(v, o, 64);
            acc[r][j] = v;
        }
    __shared__ float red[4][4][31];   // [wave][row][j]
    const int wave = tid >> 6, lane = tid & 63;
    if (lane == 0) {
#pragma unroll
        for (int r = 0; r < 4; ++r)
#pragma unroll
            for (int j = 0; j < 31; ++j) red[wave][r][j] = acc[r][j];
    }
    __syncthreads();

    if (tid < 4) {
        const int r = tid;
        const int b = b0 + r;
        float s31[31];
#pragma unroll
        for (int j = 0; j < 31; ++j)
            s31[j] = red[0][r][j] + red[1][r][j] + red[2][r][j] + red[3][r][j];

        const float s = 1.0f / sqrtf(s31[0] * (1.0f / (float)INPUT_DIM) + EPSf);

        const float a_ri = alpha_ri[0], a_wo = alpha_wo[0];
        float ri[Nn], wo[Nn];
#pragma unroll
        for (int n = 0; n < Nn; ++n) {
            ri[n] = sigmoidf_(a_ri * (s * s31[1 + n]) + read_in_p[n]);
            wo[n] = 2.0f * sigmoidf_(a_wo * (s * s31[5 + n]) + write_out_p[n]);
        }

        const float dt_c = 1e-3f + (1.0f - 1e-3f) * sigmoidf_(log_dt_c[0] + s * s31[25] + b_dtc[0]);
        const float dt_d = 1e-3f + (1.0f - 1e-3f) * sigmoidf_(log_dt_d[0] + s * s31[26] + b_dtd[0]);

        float Mmat[Nn][Nn];
#pragma unroll
        for (int i = 0; i < Nn; ++i)
#pragma unroll
            for (int j = 0; j < Nn; ++j)
                Mmat[i][j] = conserv_A[i * Nn + j] + s * s31[9 + i * Nn + j];

        float S[Nn][Nn];
#pragma unroll
        for (int i = 0; i < Nn; ++i)
#pragma unroll
            for (int j = 0; j < Nn; ++j)
                S[i][j] = dt_c * 0.5f * (Mmat[i][j] - Mmat[j][i]);

        float ehD[Nn];
#pragma unroll
        for (int n = 0; n < Nn; ++n) {
            const float v = diss_diag[n] + s * s31[27 + n];
            const float sp = (v > 20.0f) ? v : log1pf(expf(v));  // softplus
            ehD[n] = expf(-0.5f * dt_d * sp);
        }

        // Solve (I-S)X = (I+S), Gauss-Jordan (I-S ~ I, well conditioned)
        float Am[Nn][Nn], X[Nn][Nn];
#pragma unroll
        for (int i = 0; i < Nn; ++i)
#pragma unroll
            for (int j = 0; j < Nn; ++j) {
                const float id = (i == j) ? 1.0f : 0.0f;
                Am[i][j] = id - S[i][j];
                X[i][j]  = id + S[i][j];
            }
#pragma unroll
        for (int c = 0; c < Nn; ++c) {
            const float inv = 1.0f / Am[c][c];
#pragma unroll
            for (int j = 0; j < Nn; ++j) { Am[c][j] *= inv; X[c][j] *= inv; }
#pragma unroll
            for (int rr = 0; rr < Nn; ++rr) {
                if (rr == c) continue;
                const float f = Am[rr][c];
#pragma unroll
                for (int j = 0; j < Nn; ++j) { Am[rr][j] -= f * Am[c][j]; X[rr][j] -= f * X[c][j]; }
            }
        }

        float* __restrict__ P = phi_out + (size_t)b * 16;
#pragma unroll
        for (int i = 0; i < Nn; ++i)
#pragma unroll
            for (int j = 0; j < Nn; ++j)
                P[i * Nn + j] = ehD[i] * X[i][j] * ehD[j];
#pragma unroll
        for (int n = 0; n < Nn; ++n) {
            ri_out[(size_t)b * Nn + n] = ri[n];
            wo_out[(size_t)b * Nn + n] = wo[n];
        }
    }
}

// ---------------------------------------------------------------------------
// Kernel 2: branch[b,d] = sum_n ri[b,n]*x[b,n,d], emitted as bf16 hi/lo
// ---------------------------------------------------------------------------
__global__ __launch_bounds__(256) void branch_kernel(
    const float* __restrict__ x, const float* __restrict__ ri,
    unsigned short* __restrict__ bh, unsigned short* __restrict__ bl)
{
    const int g = blockIdx.x * 256 + threadIdx.x;   // over B * 512
    const int b = g >> 9;
    const int d = (g & 511) << 2;
    const float* __restrict__ xb = x + (size_t)b * INPUT_DIM;
    const float* __restrict__ r  = ri + (size_t)b * Nn;
    float4 o = make_float4(0.f, 0.f, 0.f, 0.f);
#pragma unroll
    for (int n = 0; n < Nn; ++n) {
        const float4 xv = *(const float4*)(xb + n * BLOCKD + d);
        const float rn = r[n];
        o.x = fmaf(rn, xv.x, o.x);
        o.y = fmaf(rn, xv.y, o.y);
        o.z = fmaf(rn, xv.z, o.z);
        o.w = fmaf(rn, xv.w, o.w);
    }
    ushort4 h4, l4;
    h4.x = f2bf(o.x); l4.x = f2bf(o.x - bf2f(h4.x));
    h4.y = f2bf(o.y); l4.y = f2bf(o.y - bf2f(h4.y));
    h4.z = f2bf(o.z); l4.z = f2bf(o.z - bf2f(h4.z));
    h4.w = f2bf(o.w); l4.w = f2bf(o.w - bf2f(h4.w));
    *(ushort4*)(bh + (size_t)b * EMBED + d) = h4;
    *(ushort4*)(bl + (size_t)b * EMBED + d) = l4;
}

// ---------------------------------------------------------------------------
// Kernel 3: weight transpose+split. in fp32 [R][C] -> out bf16 hi/lo [C][R]
// ---------------------------------------------------------------------------
__global__ __launch_bounds__(256) void tconv_kernel(
    const float* __restrict__ in,
    unsigned short* __restrict__ oh, unsigned short* __restrict__ ol,
    int R, int C)
{
    __shared__ float t[32][33];
    const int c0 = blockIdx.x * 32;
    const int r0 = blockIdx.y * 32;
    const int tr  = threadIdx.x >> 3;        // 0..31
    const int tc4 = (threadIdx.x & 7) * 4;   // 0..28
    const float4 v = *(const float4*)(in + (size_t)(r0 + tr) * C + c0 + tc4);
    t[tr][tc4 + 0] = v.x;
    t[tr][tc4 + 1] = v.y;
    t[tr][tc4 + 2] = v.z;
    t[tr][tc4 + 3] = v.w;
    __syncthreads();
    ushort4 h4, l4;
    {
        const float f0 = t[tc4 + 0][tr], f1 = t[tc4 + 1][tr];
        const float f2 = t[tc4 + 2][tr], f3 = t[tc4 + 3][tr];
        h4.x = f2bf(f0); l4.x = f2bf(f0 - bf2f(h4.x));
        h4.y = f2bf(f1); l4.y = f2bf(f1 - bf2f(h4.y));
        h4.z = f2bf(f2); l4.z = f2bf(f2 - bf2f(h4.z));
        h4.w = f2bf(f3); l4.w = f2bf(f3 - bf2f(h4.w));
    }
    const size_t ob = (size_t)(c0 + tr) * R + r0 + tc4;
    *(ushort4*)(oh + ob) = h4;
    *(ushort4*)(ol + ob) = l4;
}

// ---------------------------------------------------------------------------
// Kernel 4/5: bf16x3 MFMA GEMM. C = Ah*Bh + Ah*Bl + Al*Bh (lo*lo dropped).
// A row-major [M][K] bf16; B stored TRANSPOSED [N][K] bf16.
// 128x128 tile, 4 waves 2x2, 4x4 16x16x32 frags/wave.
// Per 32-wide K-chunk: phase-even stages {Ah,Bh}->bufA and runs hh MFMAs;
// phase-odd stages next chunk while computing ah*bl + al*bh with the ah/bh
// REGISTER fragments reused from phase-even (4 tile-stagings per chunk, not 6).
// LDS XOR swizzle (16B slot ^= row&3) on BOTH sides: pre-swizzled global
// source slot (linear gload dest) + same involution on ds_read [rule #21].
// C/D layout: col=lane&15, row=(lane>>4)*4+j [m89/m91].
// ---------------------------------------------------------------------------
template <int K, bool GELU>
__global__ __launch_bounds__(256) void gemm_bf16x3_kernel(
    const unsigned short* __restrict__ Ah, const unsigned short* __restrict__ Al,
    const unsigned short* __restrict__ Bh, const unsigned short* __restrict__ Bl,
    float* __restrict__ Cf,
    unsigned short* __restrict__ Ch, unsigned short* __restrict__ Cl,
    int N)
{
    constexpr int KSTEPS = K / 32;
    // bufA (hh) = smem[0..8191], bufB (ll) = smem[8192..16383]; each: A 4096 + B 4096 shorts
    __shared__ alignas(16) unsigned short smem[16384];

    const int tid = threadIdx.x;
    const int l   = tid & 63;
    const int w   = tid >> 6;
    const int wr  = w >> 1, wc = w & 1;

    // XCD-aware bijective swizzle (nwg % 8 == 0 for both GEMMs) [T1]
    const int nwg = gridDim.x * gridDim.y;
    int lin = blockIdx.y * gridDim.x + blockIdx.x;
    lin = (lin & 7) * (nwg >> 3) + (lin >> 3);
    const int bx = lin % gridDim.x;
    const int by = lin / gridDim.x;
    const int row0 = by * 128;
    const int col0 = bx * 128;

    // --- staging geometry (per-lane, hoisted) ---
    // chunk = 16 rows x 32 shorts; lane l -> row l>>2, physical 16B slot l&3.
    // Fetch logical slot s_log = (l&3) ^ ((l>>2)&3)  (XOR involution).
    const int srow   = l >> 2;
    const int skq_sw = (((l & 3) ^ ((l >> 2) & 3)) << 3);   // shorts
    const size_t aoff0 = (size_t)(row0 + (2 * w) * 16 + srow) * K + skq_sw;
    const size_t aoff1 = aoff0 + 16 * (size_t)K;
    const size_t boff0 = (size_t)(col0 + (2 * w) * 16 + srow) * K + skq_sw;
    const size_t boff1 = boff0 + 16 * (size_t)K;
    unsigned short* const ldsA = smem + (2 * w) * 512;          // bufA A-chunks
    unsigned short* const ldsB = smem + 4096 + (2 * w) * 512;   // bufA B-chunks

    // --- frag-read geometry (per-lane, hoisted) ---
    // row&3 == l&3 for all frag rows; physical slot = logical(l>>4) ^ (l&3).
    const int fr    = l & 15;
    const int kg_sw = (((l >> 4) ^ (l & 3)) << 3);              // shorts

    f32x4 acc[4][4];
    const f32x4 z4 = {0.f, 0.f, 0.f, 0.f};
#pragma unroll
    for (int m = 0; m < 4; ++m)
#pragma unroll
        for (int n = 0; n < 4; ++n) acc[m][n] = z4;

    // stage {Ap,Bp} K-chunk at koff into buffer (bufsel: 0=hh bufA, 1=ll bufB)
    auto stage = [&](const unsigned short* Ap, const unsigned short* Bp,
                     size_t koff, int bufsel) {
        const int bo = bufsel * 8192;
        gload16(Ap + aoff0 + koff, ldsA + bo);
        gload16(Ap + aoff1 + koff, ldsA + bo + 512);
        gload16(Bp + boff0 + koff, ldsB + bo);
        gload16(Bp + boff1 + koff, ldsB + bo + 512);
    };

    stage(Ah, Bh, 0, 0);
    size_t koff = 0;
    for (int kk = 0; kk < KSTEPS; ++kk) {
        // ---- phase even: hh(kk) ready in bufA after this barrier ----
        __syncthreads();
        stage(Al, Bl, koff, 1);   // ll(kk) -> bufB (in flight over hh MFMAs)

        bf16x8 ah[4], bh[4];
#pragma unroll
        for (int m = 0; m < 4; ++m)
            ah[m] = *(const bf16x8*)(smem + (wr * 64 + m * 16 + fr) * 32 + kg_sw);
#pragma unroll
        for (int n = 0; n < 4; ++n)
            bh[n] = *(const bf16x8*)(smem + 4096 + (wc * 64 + n * 16 + fr) * 32 + kg_sw);
#pragma unroll
        for (int m = 0; m < 4; ++m)
#pragma unroll
            for (int n = 0; n < 4; ++n)
                acc[m][n] = __builtin_amdgcn_mfma_f32_16x16x32_bf16(ah[m], bh[n], acc[m][n], 0, 0, 0);

        // ---- phase odd: ll(kk) ready in bufB after this barrier ----
        __syncthreads();
        if (kk + 1 < KSTEPS) stage(Ah, Bh, koff + 32, 0);   // hh(kk+1) -> bufA

        bf16x8 al[4], bl[4];
#pragma unroll
        for (int m = 0; m < 4; ++m)
            al[m] = *(const bf16x8*)(smem + 8192 + (wr * 64 + m * 16 + fr) * 32 + kg_sw);
#pragma unroll
        for (int n = 0; n < 4; ++n)
            bl[n] = *(const bf16x8*)(smem + 12288 + (wc * 64 + n * 16 + fr) * 32 + kg_sw);
#pragma unroll
        for (int m = 0; m < 4; ++m)
#pragma unroll
            for (int n = 0; n < 4; ++n) {
                acc[m][n] = __builtin_amdgcn_mfma_f32_16x16x32_bf16(ah[m], bl[n], acc[m][n], 0, 0, 0);
                acc[m][n] = __builtin_amdgcn_mfma_f32_16x16x32_bf16(al[m], bh[n], acc[m][n], 0, 0, 0);
            }
        koff += 32;
    }

    // Epilogue. D frag layout: col = lane&15, row = (lane>>4)*4 + j [m89/m91]
#pragma unroll
    for (int m = 0; m < 4; ++m) {
        const int gr0 = row0 + wr * 64 + m * 16 + (l >> 4) * 4;
#pragma unroll
        for (int j = 0; j < 4; ++j) {
            const size_t rb = (size_t)(gr0 + j) * N;
#pragma unroll
            for (int n = 0; n < 4; ++n) {
                const int gc = col0 + wc * 64 + n * 16 + fr;
                float v = acc[m][n][j];
                if (GELU) {
                    v = gelu_tanh(v);
                    const unsigned short h = f2bf(v);
                    Ch[rb + gc] = h;
                    Cl[rb + gc] = f2bf(v - bf2f(h));
                } else {
                    Cf[rb + gc] = v;
                }
            }
        }
    }
}

// ---------------------------------------------------------------------------
// Kernel 6: out[b,i,d] = sum_j Phi[b,i,j]*x[b,j,d] + wo[b,i]*y[b,d]
// ---------------------------------------------------------------------------
__global__ __launch_bounds__(256) void output_kernel(
    const float* __restrict__ x, const float* __restrict__ phi,
    const float* __restrict__ wo, const float* __restrict__ y,
    float* __restrict__ out)
{
    const int g = blockIdx.x * 256 + threadIdx.x;  // over B * 512
    const int b = g >> 9;
    const int d = (g & 511) << 2;
    const float* __restrict__ xb = x + (size_t)b * INPUT_DIM;
    float4 xj[Nn];
#pragma unroll
    for (int j = 0; j < Nn; ++j) xj[j] = *(const float4*)(xb + j * BLOCKD + d);
    const float4 yv = *(const float4*)(y + (size_t)b * EMBED + d);
    const float* __restrict__ P = phi + (size_t)b * 16;
    const float* __restrict__ wv = wo + (size_t)b * Nn;
    float* __restrict__ ob = out + (size_t)b * INPUT_DIM;
#pragma unroll
    for (int i = 0; i < Nn; ++i) {
        const float wi = wv[i];
        float4 o;
        o.x = wi * yv.x; o.y = wi * yv.y; o.z = wi * yv.z; o.w = wi * yv.w;
#pragma unroll
        for (int j = 0; j < Nn; ++j) {
            const float p = P[i * Nn + j];
            o.x = fmaf(p, xj[j].x, o.x);
            o.y = fmaf(p, xj[j].y, o.y);
            o.z = fmaf(p, xj[j].z, o.z);
            o.w = fmaf(p, xj[j].w, o.w);
        }
        *(float4*)(ob + i * BLOCKD + d) = o;
    }
}

// ---------------------------------------------------------------------------
extern "C" void kernel_launch(void* const* d_in, const int* in_sizes, int n_in,
                              void* d_out, int out_size, void* d_ws, size_t ws_size,
                              hipStream_t stream)
{
    const float* x          = (const float*)d_in[0];
    const float* read_in_p  = (const float*)d_in[1];
    const float* write_out_p= (const float*)d_in[2];
    const float* alpha_ri   = (const float*)d_in[3];
    const float* alpha_wo   = (const float*)d_in[4];
    const float* W_ri       = (const float*)d_in[5];
    const float* W_wo       = (const float*)d_in[6];
    const float* log_dt_c   = (const float*)d_in[7];
    const float* log_dt_d   = (const float*)d_in[8];
    const float* W_dtc      = (const float*)d_in[9];
    const float* b_dtc      = (const float*)d_in[10];
    const float* W_dtd      = (const float*)d_in[11];
    const float* b_dtd      = (const float*)d_in[12];
    const float* conserv_A  = (const float*)d_in[13];
    const float* W_conv     = (const float*)d_in[14];
    const float* diss_diag  = (const float*)d_in[15];
    const float* W_diss     = (const float*)d_in[16];
    const float* W1         = (const float*)d_in[17];
    const float* W2         = (const float*)d_in[18];

    // workspace layout (bytes, 256-aligned), total ~335 MB
    char* p = (char*)d_ws;
    auto alloc = [&](size_t bytes) { char* r = p; p += (bytes + 255) & ~(size_t)255; return r; };
    float*          phi = (float*)alloc((size_t)Bsz * 16 * 4);
    float*          ri  = (float*)alloc((size_t)Bsz * Nn * 4);
    float*          wo  = (float*)alloc((size_t)Bsz * Nn * 4);
    unsigned short* bh  = (unsigned short*)alloc((size_t)Bsz * EMBED * 2);
    unsigned short* bl  = (unsigned short*)alloc((size_t)Bsz * EMBED * 2);
    unsigned short* W1h = (unsigned short*)alloc((size_t)DFF * EMBED * 2);   // [8192][2048]
    unsigned short* W1l = (unsigned short*)alloc((size_t)DFF * EMBED * 2);
    unsigned short* W2h = (unsigned short*)alloc((size_t)EMBED * DFF * 2);   // [2048][8192]
    unsigned short* W2l = (unsigned short*)alloc((size_t)EMBED * DFF * 2);
    unsigned short* hh  = (unsigned short*)alloc((size_t)Bsz * DFF * 2);     // [4096][8192]
    unsigned short* hl  = (unsigned short*)alloc((size_t)Bsz * DFF * 2);
    float*          y   = (float*)alloc((size_t)Bsz * EMBED * 4);
    float*          outp = (float*)d_out;

    rowstats_kernel<<<Bsz / 4, 256, 0, stream>>>(
        x, read_in_p, write_out_p, alpha_ri, alpha_wo, W_ri, W_wo,
        log_dt_c, log_dt_d, W_dtc, b_dtc, W_dtd, b_dtd,
        conserv_A, W_conv, diss_diag, W_diss, phi, ri, wo);

    // W1 [2048][8192] -> hi/lo [8192][2048]; W2 [8192][2048] -> hi/lo [2048][8192]
    tconv_kernel<<<dim3(DFF / 32, EMBED / 32), 256, 0, stream>>>(W1, W1h, W1l, EMBED, DFF);
    tconv_kernel<<<dim3(EMBED / 32, DFF / 32), 256, 0, stream>>>(W2, W2h, W2l, DFF, EMBED);

    branch_kernel<<<(Bsz * 512) / 256, 256, 0, stream>>>(x, ri, bh, bl);

    // GEMM1: h = gelu(branch @ W1), M=4096 N=8192 K=2048 -> hh/hl bf16
    gemm_bf16x3_kernel<EMBED, true><<<dim3(DFF / 128, Bsz / 128), 256, 0, stream>>>(
        bh, bl, W1h, W1l, nullptr, hh, hl, DFF);

    // GEMM2: y = h @ W2, M=4096 N=2048 K=8192 -> fp32
    gemm_bf16x3_kernel<DFF, false><<<dim3(EMBED / 128, Bsz / 128), 256, 0, stream>>>(
        hh, hl, W2h, W2l, y, nullptr, nullptr, EMBED);

    output_kernel<<<(Bsz * 512) / 256, 256, 0, stream>>>(x, phi, wo, y, outp);
}